// Round 3
// baseline (423.053 us; speedup 1.0000x reference)
//
#include <hip/hip_runtime.h>

typedef __bf16 bf16_t;
typedef __bf16 bf16x8 __attribute__((ext_vector_type(8)));
typedef __bf16 bf16x4 __attribute__((ext_vector_type(4)));
typedef float  f32x4  __attribute__((ext_vector_type(4)));

#define MFMA16(a,b,c) __builtin_amdgcn_mfma_f32_16x16x32_bf16((a),(b),(c),0,0,0)

__device__ __forceinline__ void gl_lds16(const void* g, void* l) {
    __builtin_amdgcn_global_load_lds(
        (__attribute__((address_space(1))) void*)(g),
        (__attribute__((address_space(3))) void*)(l),
        16, 0, 0);
}

// B=2 S=4096 D=2048 HQ=32 HK=HV=8 H=32 DK=DV=64 CHUNK=64 NC=64 QKV=3072 OUT=2048
static constexpr int S_TOT   = 8192;
static constexpr int D_IN    = 2048;
static constexpr int QKV     = 3072;
static constexpr int OUT_D   = 2048;
static constexpr int NCHUNK  = 64;
static constexpr int ZSTR    = 88;   // attn score-LDS row stride (176B: 16B-aligned, ~2-way banks)

// ---------------- prep: x->bf16 convert + both weight transposes, one launch ----------------
__global__ __launch_bounds__(256)
void prep(const float* __restrict__ x, bf16_t* __restrict__ xb,
          const float* __restrict__ W_in, bf16_t* __restrict__ WinT,
          const float* __restrict__ W_out, bf16_t* __restrict__ WoutT) {
    __shared__ float tile[64][65];
    const int bid = blockIdx.x;
    const int t   = threadIdx.x;
    if (bid < 16384) {                      // cvt: 16.77M floats = 4.19M float4
        int i = bid * 256 + t;
        f32x4 v = ((const f32x4*)x)[i];
        bf16x4 o;
        o[0] = (bf16_t)v[0]; o[1] = (bf16_t)v[1]; o[2] = (bf16_t)v[2]; o[3] = (bf16_t)v[3];
        ((bf16x4*)xb)[i] = o;
        return;
    }
    // transpose fp32 [R][C] -> bf16 [C][R]
    const float* in; bf16_t* out; int R, C, bx, by;
    int tb = bid - 16384;
    if (tb < 1536) { in = W_in;  out = WinT;  R = 2048; C = 3072; bx = tb % 48; by = tb / 48; }
    else { tb -= 1536; in = W_out; out = WoutT; R = 2048; C = 2048; bx = tb % 32; by = tb / 32; }
    const int r0 = by * 64, c0 = bx * 64;
#pragma unroll
    for (int p = 0; p < 4; p++) {
        int row = p * 16 + (t >> 4);
        int col = (t & 15) * 4;
        f32x4 v = *(const f32x4*)&in[(size_t)(r0 + row) * C + c0 + col];
        tile[row][col + 0] = v[0]; tile[row][col + 1] = v[1];
        tile[row][col + 2] = v[2]; tile[row][col + 3] = v[3];
    }
    __syncthreads();
#pragma unroll
    for (int p = 0; p < 4; p++) {
        int oc  = p * 16 + (t >> 4);
        int orr = (t & 15) * 4;
        bf16x4 v;
        v[0] = (bf16_t)tile[orr + 0][oc]; v[1] = (bf16_t)tile[orr + 1][oc];
        v[2] = (bf16_t)tile[orr + 2][oc]; v[3] = (bf16_t)tile[orr + 3][oc];
        *(bf16x4*)&out[(size_t)(c0 + oc) * R + r0 + orr] = v;
    }
}

// ---------------- GEMM: C[M][N] = A[M][K]*Bt[N][K]^T, 128x128 tile, NTILE n-tiles/block ----
// Unified RF: 56 arch VGPR + 64 AGPR acc ~= 120/wave -> 4 blocks/CU hard cap.
// GEMM1 grid 768 (<=1024 capacity) x 2 tiles/block: all-resident, zero tail.
template<int OUT_BF16, int NTILE, int NSTRIDE>
__global__ __launch_bounds__(256, 4)
void gemm_bt(const bf16_t* __restrict__ A, const bf16_t* __restrict__ Bt,
             void* __restrict__ Cout, int M, int N, int K) {
    __shared__ alignas(16) bf16_t lA[128 * 32];
    __shared__ alignas(16) bf16_t lB[128 * 32];
    const int tid = threadIdx.x;
    const int m0 = blockIdx.y * 128;
    const int w = tid >> 6, lane = tid & 63;
    const int wr = (w >> 1) * 64, wc = (w & 1) * 64;
    const int l15 = lane & 15, q8 = (lane >> 4) * 8, q4 = (lane >> 4) * 4;
    const bf16_t* Ag = A + (size_t)(m0 + (tid >> 2)) * K + (tid & 3) * 8;
    const size_t rowStep = (size_t)64 * K;
    bf16_t* lA_t = lA + tid * 8;
    bf16_t* lB_t = lB + tid * 8;
#pragma unroll
    for (int tI = 0; tI < NTILE; tI++) {
        const int n0 = (blockIdx.x + tI * NSTRIDE) * 128;
        const bf16_t* Bg = Bt + (size_t)(n0 + (tid >> 2)) * K + (tid & 3) * 8;
        f32x4 acc[4][4] = {};
        for (int k0 = 0; k0 < K; k0 += 32) {
            gl_lds16(Ag + k0,           lA_t);
            gl_lds16(Ag + k0 + rowStep, lA_t + 64 * 32);
            gl_lds16(Bg + k0,           lB_t);
            gl_lds16(Bg + k0 + rowStep, lB_t + 64 * 32);
            __syncthreads();
            bf16x8 bfr[4];
#pragma unroll
            for (int nj = 0; nj < 4; nj++) bfr[nj] = *(const bf16x8*)&lB[(wc + nj * 16 + l15) * 32 + q8];
#pragma unroll
            for (int mi = 0; mi < 4; mi++) {
                bf16x8 afr = *(const bf16x8*)&lA[(wr + mi * 16 + l15) * 32 + q8];
#pragma unroll
                for (int nj = 0; nj < 4; nj++)
                    acc[mi][nj] = MFMA16(afr, bfr[nj], acc[mi][nj]);
            }
            __syncthreads();
        }
        if (OUT_BF16) {
            bf16_t* C = (bf16_t*)Cout;
#pragma unroll
            for (int mi = 0; mi < 4; mi++)
#pragma unroll
                for (int nj = 0; nj < 4; nj++)
#pragma unroll
                    for (int r = 0; r < 4; r++)
                        C[(size_t)(m0 + wr + mi * 16 + q4 + r) * N + n0 + wc + nj * 16 + l15] =
                            (bf16_t)acc[mi][nj][r];
        } else {
            float* C = (float*)Cout;
#pragma unroll
            for (int mi = 0; mi < 4; mi++)
#pragma unroll
                for (int nj = 0; nj < 4; nj++)
#pragma unroll
                    for (int r = 0; r < 4; r++)
                        C[(size_t)(m0 + wr + mi * 16 + q4 + r) * N + n0 + wc + nj * 16 + l15] =
                            acc[mi][nj][r];
        }
    }
}

// ---------------- kv_fused: proj -> vT_g (bf16 [dv][tok]) + Zc = v^T k per chunk ----------------
__global__ __launch_bounds__(64)
void kv_fused(const bf16_t* __restrict__ proj, bf16_t* __restrict__ vT_g,
              float* __restrict__ Zc) {
    const int idx = blockIdx.x;               // ((b*8+hk)*64 + c)
    const int c = idx & 63, hk = (idx >> 6) & 7, b = idx >> 9;
    const int tokBase = b * 4096 + c * 64;
    __shared__ float tk[64][65];
    __shared__ float tv[64][65];
    const int lane = threadIdx.x;
    const bf16_t* kg = proj + (size_t)tokBase * QKV + 2048 + hk * 64;
    const bf16_t* vg = proj + (size_t)tokBase * QKV + 2560 + hk * 64;
#pragma unroll
    for (int p = 0; p < 8; p++) {
        int tok = p * 8 + (lane >> 3);
        int d0  = (lane & 7) * 8;
        bf16x8 kv = *(const bf16x8*)&kg[(size_t)tok * QKV + d0];
        bf16x8 vv = *(const bf16x8*)&vg[(size_t)tok * QKV + d0];
#pragma unroll
        for (int e = 0; e < 8; e++) {
            tk[tok][d0 + e] = (float)kv[e];
            tv[tok][d0 + e] = (float)vv[e];
        }
    }
    __syncthreads();
    // write v^T to global for attn
#pragma unroll
    for (int p = 0; p < 8; p++) {
        int dv = p * 8 + (lane >> 3);
        int t0 = (lane & 7) * 8;
        bf16x8 o;
#pragma unroll
        for (int e = 0; e < 8; e++) o[e] = (bf16_t)tv[t0 + e][dv];
        *(bf16x8*)&vT_g[(size_t)idx * 4096 + dv * 64 + t0] = o;
    }
    // Zc[dv][dk] = sum_tok v[tok][dv] k[tok][dk]
    const int l15 = lane & 15, q8 = (lane >> 4) * 8, q4 = (lane >> 4) * 4;
    f32x4 acc[4][4] = {};
#pragma unroll
    for (int ks = 0; ks < 2; ks++) {
        bf16x8 af[4], bf_[4];
#pragma unroll
        for (int mi = 0; mi < 4; mi++)
#pragma unroll
            for (int e = 0; e < 8; e++) af[mi][e] = (bf16_t)tv[ks * 32 + q8 + e][mi * 16 + l15];
#pragma unroll
        for (int nj = 0; nj < 4; nj++)
#pragma unroll
            for (int e = 0; e < 8; e++) bf_[nj][e] = (bf16_t)tk[ks * 32 + q8 + e][nj * 16 + l15];
#pragma unroll
        for (int mi = 0; mi < 4; mi++)
#pragma unroll
            for (int nj = 0; nj < 4; nj++)
                acc[mi][nj] = MFMA16(af[mi], bf_[nj], acc[mi][nj]);
    }
    float* zout = Zc + (size_t)idx * 4096;
#pragma unroll
    for (int mi = 0; mi < 4; mi++)
#pragma unroll
        for (int nj = 0; nj < 4; nj++)
#pragma unroll
            for (int r = 0; r < 4; r++)
                zout[(mi * 16 + q4 + r) * 64 + nj * 16 + l15] = acc[mi][nj][r];
}

// ---------------- prefix state (+S0), emit bf16 prefixes + final state ----------------
__global__ __launch_bounds__(256)
void prefix_state(const float* __restrict__ Zc, const float* __restrict__ S0,
                  bf16_t* __restrict__ Zp, float* __restrict__ SfOut) {
    const int slice = blockIdx.x & 15;
    const int bh = blockIdx.x >> 4;
    const int h = bh & 31, b = bh >> 5;
    const int hk = h >> 2;
    const int e = slice * 256 + threadIdx.x;      // e = dv*64 + dk
    const int dv = e >> 6, dk = e & 63;
    float acc = S0[(size_t)b * 131072 + h * 4096 + dk * 64 + dv];   // S0[b][h][dk][dv]
    const float* zc = Zc + ((size_t)(b * 8 + hk) * 64) * 4096 + e;
    bf16_t* zp = Zp + ((size_t)(b * 32 + h) * 64) * 4096 + e;
#pragma unroll 4
    for (int c = 0; c < NCHUNK; c++) {
        zp[(size_t)c * 4096] = (bf16_t)acc;
        acc += zc[(size_t)c * 4096];
    }
    SfOut[(size_t)b * 131072 + h * 4096 + dk * 64 + dv] = acc;
}

// ---------------- attn: 4 GQA heads per block (one wave each) ----------------
__global__ __launch_bounds__(256)
void attn_chunk(const bf16_t* __restrict__ proj, const bf16_t* __restrict__ vT_g,
                const bf16_t* __restrict__ Zp, bf16_t* __restrict__ O) {
    const int idx = blockIdx.x;                 // (b*64 + c)*8 + hk
    const int hk = idx & 7, c = (idx >> 3) & 63, b = idx >> 9;
    const int g = threadIdx.x >> 6, lane = threadIdx.x & 63;
    const int h = hk * 4 + g;
    const int tokBase = b * 4096 + c * 64;
    __shared__ alignas(16) bf16_t zs_all[4][64 * ZSTR];
    bf16_t* zs = zs_all[g];
    const int l15 = lane & 15, q8 = (lane >> 4) * 8, q4 = (lane >> 4) * 4;
    const bf16_t* qrow  = proj + (size_t)tokBase * QKV + h * 64;            // [ti][dk]
    const bf16_t* krow  = proj + (size_t)tokBase * QKV + 2048 + hk * 64;    // [tj][dk]
    const bf16_t* zrow  = Zp + (((size_t)(b * 32 + h)) * 64 + c) * 4096;    // [dv][dk]
    const bf16_t* vTrow = vT_g + ((size_t)(b * 8 + hk) * 64 + c) * 4096;    // [dv][tok]

    bf16x8 qf[2][4];
#pragma unroll
    for (int ks = 0; ks < 2; ks++)
#pragma unroll
        for (int mi = 0; mi < 4; mi++)
            qf[ks][mi] = *(const bf16x8*)&qrow[(size_t)(mi * 16 + l15) * QKV + ks * 32 + q8];

    // o = q @ S (Zp holds S^T as [dv][dk])
    f32x4 oacc[4][4] = {};
#pragma unroll
    for (int ks = 0; ks < 2; ks++) {
        bf16x8 zf[4];
#pragma unroll
        for (int nj = 0; nj < 4; nj++) zf[nj] = *(const bf16x8*)&zrow[(nj * 16 + l15) * 64 + ks * 32 + q8];
#pragma unroll
        for (int mi = 0; mi < 4; mi++)
#pragma unroll
            for (int nj = 0; nj < 4; nj++)
                oacc[mi][nj] = MFMA16(qf[ks][mi], zf[nj], oacc[mi][nj]);
    }
    // scores = q @ k^T (lower-triangle tiles only)
    f32x4 sacc[4][4] = {};
#pragma unroll
    for (int ks = 0; ks < 2; ks++) {
        bf16x8 kf[4];
#pragma unroll
        for (int nj = 0; nj < 4; nj++) kf[nj] = *(const bf16x8*)&krow[(size_t)(nj * 16 + l15) * QKV + ks * 32 + q8];
#pragma unroll
        for (int mi = 0; mi < 4; mi++)
#pragma unroll
            for (int nj = 0; nj < 4; nj++)
                if (mi >= nj) sacc[mi][nj] = MFMA16(qf[ks][mi], kf[nj], sacc[mi][nj]);
    }
    // mask + store scores bf16 [ti][tj], stride 88
#pragma unroll
    for (int mi = 0; mi < 4; mi++)
#pragma unroll
        for (int nj = 0; nj < 4; nj++)
#pragma unroll
            for (int r = 0; r < 4; r++) {
                int ti = mi * 16 + q4 + r, tj = nj * 16 + l15;
                float v = (ti >= tj) ? sacc[mi][nj][r] : 0.0f;
                zs[ti * ZSTR + tj] = (bf16_t)v;
            }
    __syncthreads();
    // o += scores @ v
#pragma unroll
    for (int ks = 0; ks < 2; ks++) {
        bf16x8 sf[4], vf[4];
#pragma unroll
        for (int mi = 0; mi < 4; mi++) sf[mi] = *(const bf16x8*)&zs[(mi * 16 + l15) * ZSTR + ks * 32 + q8];
#pragma unroll
        for (int nj = 0; nj < 4; nj++) vf[nj] = *(const bf16x8*)&vTrow[(nj * 16 + l15) * 64 + ks * 32 + q8];
#pragma unroll
        for (int mi = 0; mi < 4; mi++)
#pragma unroll
            for (int nj = 0; nj < 4; nj++)
                oacc[mi][nj] = MFMA16(sf[mi], vf[nj], oacc[mi][nj]);
    }
    bf16_t* og = O + (size_t)tokBase * OUT_D + h * 64;
#pragma unroll
    for (int mi = 0; mi < 4; mi++)
#pragma unroll
        for (int nj = 0; nj < 4; nj++)
#pragma unroll
            for (int r = 0; r < 4; r++)
                og[(size_t)(mi * 16 + q4 + r) * OUT_D + nj * 16 + l15] = (bf16_t)oacc[mi][nj][r];
}

// ---------------- launcher ----------------
extern "C" void kernel_launch(void* const* d_in, const int* in_sizes, int n_in,
                              void* d_out, int out_size, void* d_ws, size_t ws_size,
                              hipStream_t stream) {
    const float* x     = (const float*)d_in[0];
    const float* S0    = (const float*)d_in[1];
    const float* W_in  = (const float*)d_in[2];
    const float* W_out = (const float*)d_in[3];

    char* ws = (char*)d_ws;
    bf16_t* xb    = (bf16_t*)(ws + 0);            // 33.5 MB; dead after GEMM1
    bf16_t* WinT  = (bf16_t*)(ws + 33554432);     // 12.6 MB; dead after GEMM1
    bf16_t* WoutT = (bf16_t*)(ws + 46137344);     // 8.4 MB; live until GEMM2
    bf16_t* proj  = (bf16_t*)(ws + 54525952);     // 50.3 MB
    float*  Zc    = (float*) (ws + 104857600);    // 16.8 MB
    bf16_t* Zp    = (bf16_t*)(ws + 121634816);    // 33.5 MB
    bf16_t* vT_g  = (bf16_t*)(ws + 0);            // 8.4 MB, overlays dead xb
    bf16_t* Ob    = (bf16_t*)(ws + 8388608);      // 33.5 MB, overlays dead xb/WinT

    float* outMain  = (float*)d_out;
    float* outState = (float*)d_out + (size_t)S_TOT * OUT_D;

    prep<<<16384 + 1536 + 1024, 256, 0, stream>>>(x, xb, W_in, WinT, W_out, WoutT);
    gemm_bt<1, 2, 12><<<dim3(12, 64), 256, 0, stream>>>(xb, WinT, proj, S_TOT, QKV, D_IN);
    kv_fused<<<1024, 64, 0, stream>>>(proj, vT_g, Zc);
    prefix_state<<<1024, 256, 0, stream>>>(Zc, S0, Zp, outState);
    attn_chunk<<<1024, 256, 0, stream>>>(proj, vT_g, Zp, Ob);
    gemm_bt<0, 1, 16><<<dim3(16, 64), 256, 0, stream>>>(Ob, WoutT, outMain, S_TOT, OUT_D, OUT_D);
}

// Round 4
// 371.181 us; speedup vs baseline: 1.1397x; 1.1397x over previous
//
#include <hip/hip_runtime.h>

typedef __bf16 bf16_t;
typedef __bf16 bf16x8 __attribute__((ext_vector_type(8)));
typedef __bf16 bf16x4 __attribute__((ext_vector_type(4)));
typedef float  f32x4  __attribute__((ext_vector_type(4)));

#define MFMA16(a,b,c) __builtin_amdgcn_mfma_f32_16x16x32_bf16((a),(b),(c),0,0,0)

__device__ __forceinline__ void gl_lds16(const void* g, void* l) {
    __builtin_amdgcn_global_load_lds(
        (__attribute__((address_space(1))) void*)(g),
        (__attribute__((address_space(3))) void*)(l),
        16, 0, 0);
}

// B=2 S=4096 D=2048 HQ=32 HK=HV=8 H=32 DK=DV=64 CHUNK=64 NC=64 QKV=3072 OUT=2048
static constexpr int S_TOT   = 8192;
static constexpr int D_IN    = 2048;
static constexpr int QKV     = 3072;
static constexpr int OUT_D   = 2048;
static constexpr int NCHUNK  = 64;
static constexpr int ZSTR    = 88;

// ---------------- prep: x->bf16 convert + both weight transposes, one launch ----------------
__global__ __launch_bounds__(256)
void prep(const float* __restrict__ x, bf16_t* __restrict__ xb,
          const float* __restrict__ W_in, bf16_t* __restrict__ WinT,
          const float* __restrict__ W_out, bf16_t* __restrict__ WoutT) {
    __shared__ float tile[64][65];
    const int bid = blockIdx.x;
    const int t   = threadIdx.x;
    if (bid < 16384) {
        int i = bid * 256 + t;
        f32x4 v = ((const f32x4*)x)[i];
        bf16x4 o;
        o[0] = (bf16_t)v[0]; o[1] = (bf16_t)v[1]; o[2] = (bf16_t)v[2]; o[3] = (bf16_t)v[3];
        ((bf16x4*)xb)[i] = o;
        return;
    }
    const float* in; bf16_t* out; int R, C, bx, by;
    int tb = bid - 16384;
    if (tb < 1536) { in = W_in;  out = WinT;  R = 2048; C = 3072; bx = tb % 48; by = tb / 48; }
    else { tb -= 1536; in = W_out; out = WoutT; R = 2048; C = 2048; bx = tb % 32; by = tb / 32; }
    const int r0 = by * 64, c0 = bx * 64;
#pragma unroll
    for (int p = 0; p < 4; p++) {
        int row = p * 16 + (t >> 4);
        int col = (t & 15) * 4;
        f32x4 v = *(const f32x4*)&in[(size_t)(r0 + row) * C + c0 + col];
        tile[row][col + 0] = v[0]; tile[row][col + 1] = v[1];
        tile[row][col + 2] = v[2]; tile[row][col + 3] = v[3];
    }
    __syncthreads();
#pragma unroll
    for (int p = 0; p < 4; p++) {
        int oc  = p * 16 + (t >> 4);
        int orr = (t & 15) * 4;
        bf16x4 v;
        v[0] = (bf16_t)tile[orr + 0][oc]; v[1] = (bf16_t)tile[orr + 1][oc];
        v[2] = (bf16_t)tile[orr + 2][oc]; v[3] = (bf16_t)tile[orr + 3][oc];
        *(bf16x4*)&out[(size_t)(c0 + oc) * R + r0 + orr] = v;
    }
}

// ---------------- GEMM: C[M][N] = A[M][K]*Bt[N][K]^T, 128x128 tile, BK=64 ----------------
// BK=64: 32 MFMA per barrier-pair (2x amortization vs BK=32), 32KB LDS keeps 4 blk/CU.
// XOR swizzle: LDS (row,cc) holds global (row, cc^(row&7)); applied to the global
// source per-lane (per-thread constant), so global_load_lds dest stays contiguous.
// Frag reads then hit all 32 banks at <=2-way.
template<int OUT_BF16>
__global__ __launch_bounds__(256, 4)
void gemm_bt(const bf16_t* __restrict__ A, const bf16_t* __restrict__ Bt,
             void* __restrict__ Cout, int M, int N, int K) {
    __shared__ alignas(16) bf16_t lA[128 * 64];
    __shared__ alignas(16) bf16_t lB[128 * 64];
    const int tid = threadIdx.x;
    const int m0 = blockIdx.y * 128;
    const int n0 = blockIdx.x * 128;
    const int w = tid >> 6, lane = tid & 63;
    const int wr = (w >> 1) * 64, wc = (w & 1) * 64;
    const int l15 = lane & 15, q = lane >> 4, q4 = q * 4;
    const int trow = tid >> 3;                    // 0..31
    const int tcc  = (tid & 7) ^ (trow & 7);      // swizzled source col-chunk
    const bf16_t* Ag = A + (size_t)(m0 + trow) * K + tcc * 8;
    const bf16_t* Bg = Bt + (size_t)(n0 + trow) * K + tcc * 8;
    bf16_t* lA_t = lA + tid * 8;
    bf16_t* lB_t = lB + tid * 8;
    const size_t rs = (size_t)32 * K;
    const int cc0 = (q)     ^ (l15 & 7);          // read chunk, ksub=0
    const int cc1 = (4 + q) ^ (l15 & 7);          // read chunk, ksub=1
    f32x4 acc[4][4] = {};
    for (int k0 = 0; k0 < K; k0 += 64) {
#pragma unroll
        for (int j = 0; j < 4; j++) {
            gl_lds16(Ag + k0 + j * rs, lA_t + j * 2048);
            gl_lds16(Bg + k0 + j * rs, lB_t + j * 2048);
        }
        __syncthreads();
#pragma unroll
        for (int ksub = 0; ksub < 2; ksub++) {
            const int cc = ksub ? cc1 : cc0;
            bf16x8 bfr[4];
#pragma unroll
            for (int nj = 0; nj < 4; nj++)
                bfr[nj] = *(const bf16x8*)&lB[(wc + nj * 16 + l15) * 64 + cc * 8];
#pragma unroll
            for (int mi = 0; mi < 4; mi++) {
                bf16x8 afr = *(const bf16x8*)&lA[(wr + mi * 16 + l15) * 64 + cc * 8];
#pragma unroll
                for (int nj = 0; nj < 4; nj++)
                    acc[mi][nj] = MFMA16(afr, bfr[nj], acc[mi][nj]);
            }
        }
        __syncthreads();
    }
    if (OUT_BF16) {
        bf16_t* C = (bf16_t*)Cout;
#pragma unroll
        for (int mi = 0; mi < 4; mi++)
#pragma unroll
            for (int nj = 0; nj < 4; nj++)
#pragma unroll
                for (int r = 0; r < 4; r++)
                    C[(size_t)(m0 + wr + mi * 16 + q4 + r) * N + n0 + wc + nj * 16 + l15] =
                        (bf16_t)acc[mi][nj][r];
    } else {
        float* C = (float*)Cout;
#pragma unroll
        for (int mi = 0; mi < 4; mi++)
#pragma unroll
            for (int nj = 0; nj < 4; nj++)
#pragma unroll
                for (int r = 0; r < 4; r++)
                    C[(size_t)(m0 + wr + mi * 16 + q4 + r) * N + n0 + wc + nj * 16 + l15] =
                        acc[mi][nj][r];
    }
}

// ---------------- kv_fused: proj -> vT_g (bf16 [dv][tok]) + Zc = v^T k per chunk ----------------
__global__ __launch_bounds__(64)
void kv_fused(const bf16_t* __restrict__ proj, bf16_t* __restrict__ vT_g,
              float* __restrict__ Zc) {
    const int idx = blockIdx.x;               // ((b*8+hk)*64 + c)
    const int c = idx & 63, hk = (idx >> 6) & 7, b = idx >> 9;
    const int tokBase = b * 4096 + c * 64;
    __shared__ float tk[64][65];
    __shared__ float tv[64][65];
    const int lane = threadIdx.x;
    const bf16_t* kg = proj + (size_t)tokBase * QKV + 2048 + hk * 64;
    const bf16_t* vg = proj + (size_t)tokBase * QKV + 2560 + hk * 64;
#pragma unroll
    for (int p = 0; p < 8; p++) {
        int tok = p * 8 + (lane >> 3);
        int d0  = (lane & 7) * 8;
        bf16x8 kv = *(const bf16x8*)&kg[(size_t)tok * QKV + d0];
        bf16x8 vv = *(const bf16x8*)&vg[(size_t)tok * QKV + d0];
#pragma unroll
        for (int e = 0; e < 8; e++) {
            tk[tok][d0 + e] = (float)kv[e];
            tv[tok][d0 + e] = (float)vv[e];
        }
    }
    __syncthreads();
#pragma unroll
    for (int p = 0; p < 8; p++) {
        int dv = p * 8 + (lane >> 3);
        int t0 = (lane & 7) * 8;
        bf16x8 o;
#pragma unroll
        for (int e = 0; e < 8; e++) o[e] = (bf16_t)tv[t0 + e][dv];
        *(bf16x8*)&vT_g[(size_t)idx * 4096 + dv * 64 + t0] = o;
    }
    const int l15 = lane & 15, q8 = (lane >> 4) * 8, q4 = (lane >> 4) * 4;
    f32x4 acc[4][4] = {};
#pragma unroll
    for (int ks = 0; ks < 2; ks++) {
        bf16x8 af[4], bf_[4];
#pragma unroll
        for (int mi = 0; mi < 4; mi++)
#pragma unroll
            for (int e = 0; e < 8; e++) af[mi][e] = (bf16_t)tv[ks * 32 + q8 + e][mi * 16 + l15];
#pragma unroll
        for (int nj = 0; nj < 4; nj++)
#pragma unroll
            for (int e = 0; e < 8; e++) bf_[nj][e] = (bf16_t)tk[ks * 32 + q8 + e][nj * 16 + l15];
#pragma unroll
        for (int mi = 0; mi < 4; mi++)
#pragma unroll
            for (int nj = 0; nj < 4; nj++)
                acc[mi][nj] = MFMA16(af[mi], bf_[nj], acc[mi][nj]);
    }
    float* zout = Zc + (size_t)idx * 4096;
#pragma unroll
    for (int mi = 0; mi < 4; mi++)
#pragma unroll
        for (int nj = 0; nj < 4; nj++)
#pragma unroll
            for (int r = 0; r < 4; r++)
                zout[(mi * 16 + q4 + r) * 64 + nj * 16 + l15] = acc[mi][nj][r];
}

// ---------------- prefix state (+S0), emit bf16 prefixes + final state ----------------
__global__ __launch_bounds__(256)
void prefix_state(const float* __restrict__ Zc, const float* __restrict__ S0,
                  bf16_t* __restrict__ Zp, float* __restrict__ SfOut) {
    const int slice = blockIdx.x & 15;
    const int bh = blockIdx.x >> 4;
    const int h = bh & 31, b = bh >> 5;
    const int hk = h >> 2;
    const int e = slice * 256 + threadIdx.x;      // e = dv*64 + dk
    const int dv = e >> 6, dk = e & 63;
    float acc = S0[(size_t)b * 131072 + h * 4096 + dk * 64 + dv];
    const float* zc = Zc + ((size_t)(b * 8 + hk) * 64) * 4096 + e;
    bf16_t* zp = Zp + ((size_t)(b * 32 + h) * 64) * 4096 + e;
#pragma unroll 4
    for (int c = 0; c < NCHUNK; c++) {
        zp[(size_t)c * 4096] = (bf16_t)acc;
        acc += zc[(size_t)c * 4096];
    }
    SfOut[(size_t)b * 131072 + h * 4096 + dk * 64 + dv] = acc;
}

// ---------------- attn: 4 GQA heads per block (one wave each) ----------------
__global__ __launch_bounds__(256)
void attn_chunk(const bf16_t* __restrict__ proj, const bf16_t* __restrict__ vT_g,
                const bf16_t* __restrict__ Zp, bf16_t* __restrict__ O) {
    const int idx = blockIdx.x;                 // (b*64 + c)*8 + hk
    const int hk = idx & 7, c = (idx >> 3) & 63, b = idx >> 9;
    const int g = threadIdx.x >> 6, lane = threadIdx.x & 63;
    const int h = hk * 4 + g;
    const int tokBase = b * 4096 + c * 64;
    __shared__ alignas(16) bf16_t zs_all[4][64 * ZSTR];
    bf16_t* zs = zs_all[g];
    const int l15 = lane & 15, q8 = (lane >> 4) * 8, q4 = (lane >> 4) * 4;
    const bf16_t* qrow  = proj + (size_t)tokBase * QKV + h * 64;
    const bf16_t* krow  = proj + (size_t)tokBase * QKV + 2048 + hk * 64;
    const bf16_t* zrow  = Zp + (((size_t)(b * 32 + h)) * 64 + c) * 4096;
    const bf16_t* vTrow = vT_g + ((size_t)(b * 8 + hk) * 64 + c) * 4096;

    bf16x8 qf[2][4];
#pragma unroll
    for (int ks = 0; ks < 2; ks++)
#pragma unroll
        for (int mi = 0; mi < 4; mi++)
            qf[ks][mi] = *(const bf16x8*)&qrow[(size_t)(mi * 16 + l15) * QKV + ks * 32 + q8];

    f32x4 oacc[4][4] = {};
#pragma unroll
    for (int ks = 0; ks < 2; ks++) {
        bf16x8 zf[4];
#pragma unroll
        for (int nj = 0; nj < 4; nj++) zf[nj] = *(const bf16x8*)&zrow[(nj * 16 + l15) * 64 + ks * 32 + q8];
#pragma unroll
        for (int mi = 0; mi < 4; mi++)
#pragma unroll
            for (int nj = 0; nj < 4; nj++)
                oacc[mi][nj] = MFMA16(qf[ks][mi], zf[nj], oacc[mi][nj]);
    }
    f32x4 sacc[4][4] = {};
#pragma unroll
    for (int ks = 0; ks < 2; ks++) {
        bf16x8 kf[4];
#pragma unroll
        for (int nj = 0; nj < 4; nj++) kf[nj] = *(const bf16x8*)&krow[(size_t)(nj * 16 + l15) * QKV + ks * 32 + q8];
#pragma unroll
        for (int mi = 0; mi < 4; mi++)
#pragma unroll
            for (int nj = 0; nj < 4; nj++)
                if (mi >= nj) sacc[mi][nj] = MFMA16(qf[ks][mi], kf[nj], sacc[mi][nj]);
    }
#pragma unroll
    for (int mi = 0; mi < 4; mi++)
#pragma unroll
        for (int nj = 0; nj < 4; nj++)
#pragma unroll
            for (int r = 0; r < 4; r++) {
                int ti = mi * 16 + q4 + r, tj = nj * 16 + l15;
                float v = (ti >= tj) ? sacc[mi][nj][r] : 0.0f;
                zs[ti * ZSTR + tj] = (bf16_t)v;
            }
    __syncthreads();
#pragma unroll
    for (int ks = 0; ks < 2; ks++) {
        bf16x8 sf[4], vf[4];
#pragma unroll
        for (int mi = 0; mi < 4; mi++) sf[mi] = *(const bf16x8*)&zs[(mi * 16 + l15) * ZSTR + ks * 32 + q8];
#pragma unroll
        for (int nj = 0; nj < 4; nj++) vf[nj] = *(const bf16x8*)&vTrow[(nj * 16 + l15) * 64 + ks * 32 + q8];
#pragma unroll
        for (int mi = 0; mi < 4; mi++)
#pragma unroll
            for (int nj = 0; nj < 4; nj++)
                oacc[mi][nj] = MFMA16(sf[mi], vf[nj], oacc[mi][nj]);
    }
    bf16_t* og = O + (size_t)tokBase * OUT_D + h * 64;
#pragma unroll
    for (int mi = 0; mi < 4; mi++)
#pragma unroll
        for (int nj = 0; nj < 4; nj++)
#pragma unroll
            for (int r = 0; r < 4; r++)
                og[(size_t)(mi * 16 + q4 + r) * OUT_D + nj * 16 + l15] = (bf16_t)oacc[mi][nj][r];
}

// ---------------- launcher ----------------
extern "C" void kernel_launch(void* const* d_in, const int* in_sizes, int n_in,
                              void* d_out, int out_size, void* d_ws, size_t ws_size,
                              hipStream_t stream) {
    const float* x     = (const float*)d_in[0];
    const float* S0    = (const float*)d_in[1];
    const float* W_in  = (const float*)d_in[2];
    const float* W_out = (const float*)d_in[3];

    char* ws = (char*)d_ws;
    bf16_t* xb    = (bf16_t*)(ws + 0);            // 33.5 MB; dead after GEMM1
    bf16_t* WinT  = (bf16_t*)(ws + 33554432);     // 12.6 MB; dead after GEMM1
    bf16_t* WoutT = (bf16_t*)(ws + 46137344);     // 8.4 MB; live until GEMM2
    bf16_t* proj  = (bf16_t*)(ws + 54525952);     // 50.3 MB
    float*  Zc    = (float*) (ws + 104857600);    // 16.8 MB
    bf16_t* Zp    = (bf16_t*)(ws + 121634816);    // 33.5 MB
    bf16_t* vT_g  = (bf16_t*)(ws + 0);            // 8.4 MB, overlays dead xb
    bf16_t* Ob    = (bf16_t*)(ws + 8388608);      // 33.5 MB, overlays dead xb/WinT

    float* outMain  = (float*)d_out;
    float* outState = (float*)d_out + (size_t)S_TOT * OUT_D;

    prep<<<16384 + 1536 + 1024, 256, 0, stream>>>(x, xb, W_in, WinT, W_out, WoutT);
    gemm_bt<1><<<dim3(24, 64), 256, 0, stream>>>(xb, WinT, proj, S_TOT, QKV, D_IN);
    kv_fused<<<1024, 64, 0, stream>>>(proj, vT_g, Zc);
    prefix_state<<<1024, 256, 0, stream>>>(Zc, S0, Zp, outState);
    attn_chunk<<<1024, 256, 0, stream>>>(proj, vT_g, Zp, Ob);
    gemm_bt<0><<<dim3(16, 64), 256, 0, stream>>>(Ob, WoutT, outMain, S_TOT, OUT_D, OUT_D);
}